// Round 4
// baseline (48.260 us; speedup 1.0000x reference)
//
#include <hip/hip_runtime.h>
#include <hip/hip_bf16.h>
#include <math.h>

// ---------------------------------------------------------------------------
// KAN 2-layer forward, bf16-MFMA, pipelined split-K GEMM.
//   layer1 GEMM: C(128,256) = A(128,K) * W(K,256), K = 3072 * 12 (padded)
//     per input i: k-slots 0..7 = cubic B-spline basis, 8 = silu, 9..11 = pad
//   grid (8 n-tiles x 64 k-chunks) = 512 blocks = 2/CU exactly.
//   chunk = 48 inputs = 6 stages of 8 i (96 k = 3 MFMA k-steps).
//   Per stage: convert regs->LDS(dbuf) -> barrier -> prefetch s+2 -> MFMA.
//   f32 partial[chunk][b][o]; reduce fused with selu + layer2.
// ---------------------------------------------------------------------------

#define B_DIM   128
#define IN1     3072
#define OUT1    256
#define NB      8
#define OUT2    10

#define CI      48                  // inputs per chunk
#define NCH     (IN1 / CI)          // 64 chunks
#define NS      6                   // stages per chunk
#define SI      8                   // inputs per stage
#define BN      32                  // o-tile per block
#define ASTR_B  256                 // A LDS row stride (bytes), 96 k used
#define BSTR_B  192                 // B LDS row stride (bytes)

typedef short  bf16x8 __attribute__((ext_vector_type(8)));
typedef float  f32x4  __attribute__((ext_vector_type(4)));
typedef unsigned short ushort_t;

__device__ __forceinline__ ushort_t f2bf(float f) {
    union { __hip_bfloat16 h; ushort_t u; } v;
    v.h = __float2bfloat16(f);
    return v.u;
}

// cardinal cubic B-spline basis (8 funcs) + silu, closed form (== Cox-de Boor
// recursion of the reference on the uniform extended grid [-2.2,2.2], h=0.4).
__device__ __forceinline__ void basis_silu(float x, float w[8], float& sil) {
    sil = x / (1.0f + __expf(-x));
    float u  = (x + 2.2f) * 2.5f;
    float uf = floorf(u);
    int   j  = (int)uf;
    float t  = u - uf;
    float omt = 1.0f - t;
    float t2 = t * t, t3 = t2 * t;
    float w0 = omt * omt * omt * (1.0f / 6.0f);
    float w1 = (3.0f * t3 - 6.0f * t2 + 4.0f) * (1.0f / 6.0f);
    float w2 = (-3.0f * t3 + 3.0f * t2 + 3.0f * t + 1.0f) * (1.0f / 6.0f);
    float w3 = t3 * (1.0f / 6.0f);
    bool valid = (u >= 0.0f) && (u < 11.0f);
#pragma unroll
    for (int g = 0; g < 8; ++g) {
        int m = g - j + 3;
        float v = (m == 0) ? w0 : (m == 1) ? w1 : (m == 2) ? w2 : (m == 3) ? w3 : 0.0f;
        w[g] = valid ? v : 0.0f;
    }
}

__device__ __forceinline__ float selu_f(float x) {
    const float scale = 1.0507009873554805f;
    const float alpha = 1.6732632423543772f;
    return (x > 0.0f) ? scale * x : scale * alpha * (__expf(x) - 1.0f);
}

// ---------------------------------------------------------------------------
// Kernel T: transpose x (128,3072) -> xT (3072,128)
// ---------------------------------------------------------------------------
__global__ __launch_bounds__(256) void ktranspose(const float* __restrict__ x,
                                                  float* __restrict__ xT) {
    __shared__ float t[32][33];
    int bx = blockIdx.x, by = blockIdx.y;
    int tx = threadIdx.x, ty = threadIdx.y;
#pragma unroll
    for (int k = 0; k < 4; ++k)
        t[ty + k * 8][tx] = x[(by * 32 + ty + k * 8) * IN1 + bx * 32 + tx];
    __syncthreads();
#pragma unroll
    for (int k = 0; k < 4; ++k)
        xT[(bx * 32 + ty + k * 8) * B_DIM + by * 32 + tx] = t[tx][ty + k * 8];
}

// ---------------------------------------------------------------------------
// Kernel G: pipelined MFMA GEMM chunk.  512 threads (8 waves).
//   wave w: nt = w&1 (16 n-cols), mg = w>>1 (pair of 16-row m-tiles).
// ---------------------------------------------------------------------------
__global__ __launch_bounds__(512) void kan_gemm(const float* __restrict__ xT,
                                                const float* __restrict__ coef1,
                                                const float* __restrict__ sb1,
                                                const float* __restrict__ ssp1,
                                                float* __restrict__ partial) {
    __shared__ ushort_t Asm[2][B_DIM * (ASTR_B / 2)];   // 64 KB
    __shared__ ushort_t Bsm[2][BN * (BSTR_B / 2)];      // 12 KB

    const int tid   = threadIdx.x;
    const int o0    = blockIdx.x * BN;
    const int chunk = blockIdx.y;
    const int i_base = chunk * CI;

    // staging maps
    const int bq  = tid >> 3;           // 0..63 -> rows bq, bq+64
    const int iiA = tid & 7;
    const int ol  = (tid & 255) >> 3;   // 0..31 (W valid for tid<256)
    const int iiW = tid & 7;
    const bool doW = (tid < 256);

    // MFMA maps
    const int w = tid >> 6, l = tid & 63;
    const int nt = w & 1, mg = w >> 1;
    const int row16 = l & 15, k16 = l >> 4;

    // prefetch register sets (indices become static under full unroll)
    float  xv0[2], xv1[2];
    float4 c0r[2], c1r[2];
    float  sspr[2], sbr[2];

#define LOADS(set, ss)                                                          \
    {                                                                           \
        const int ib = i_base + (ss) * SI;                                      \
        xv0[set] = xT[(size_t)(ib + iiA) * B_DIM + bq];                         \
        xv1[set] = xT[(size_t)(ib + iiA) * B_DIM + bq + 64];                    \
        if (doW) {                                                              \
            const size_t e = (size_t)(o0 + ol) * IN1 + (ib + iiW);              \
            c0r[set] = *reinterpret_cast<const float4*>(coef1 + e * NB);        \
            c1r[set] = *reinterpret_cast<const float4*>(coef1 + e * NB + 4);    \
            sspr[set] = ssp1[e];                                                \
            sbr[set]  = sb1[e];                                                 \
        }                                                                       \
    }

    f32x4 acc0 = {0.f, 0.f, 0.f, 0.f};
    f32x4 acc1 = {0.f, 0.f, 0.f, 0.f};

    LOADS(0, 0)
    LOADS(1, 1)

#pragma unroll
    for (int s = 0; s < NS; ++s) {
        const int set = s & 1;
        char* Aw = (char*)&Asm[set][0];
        char* Bw = (char*)&Bsm[set][0];

        // ---- convert regs -> LDS ----
        {
            float xa[2] = {xv0[set], xv1[set]};
#pragma unroll
            for (int p = 0; p < 2; ++p) {
                const int b = bq + p * 64;
                float bs[8], sil;
                basis_silu(xa[p], bs, sil);
                ushort4 pa, pb, pc;
                pa.x = f2bf(bs[0]); pa.y = f2bf(bs[1]); pa.z = f2bf(bs[2]); pa.w = f2bf(bs[3]);
                pb.x = f2bf(bs[4]); pb.y = f2bf(bs[5]); pb.z = f2bf(bs[6]); pb.w = f2bf(bs[7]);
                pc.x = f2bf(sil);   pc.y = 0;           pc.z = 0;           pc.w = 0;
                char* rowp = Aw + b * ASTR_B;
                const int sw = (b & 7) << 4;
                *reinterpret_cast<ushort4*>(rowp + ((iiA * 24 + 0)  ^ sw)) = pa;
                *reinterpret_cast<ushort4*>(rowp + ((iiA * 24 + 8)  ^ sw)) = pb;
                *reinterpret_cast<ushort4*>(rowp + ((iiA * 24 + 16) ^ sw)) = pc;
            }
            if (doW) {
                const float sspv = sspr[set], sbv = sbr[set];
                const float4 c0 = c0r[set], c1 = c1r[set];
                ushort4 pa, pb, pc;
                pa.x = f2bf(c0.x * sspv); pa.y = f2bf(c0.y * sspv);
                pa.z = f2bf(c0.z * sspv); pa.w = f2bf(c0.w * sspv);
                pb.x = f2bf(c1.x * sspv); pb.y = f2bf(c1.y * sspv);
                pb.z = f2bf(c1.z * sspv); pb.w = f2bf(c1.w * sspv);
                pc.x = f2bf(sbv); pc.y = 0; pc.z = 0; pc.w = 0;
                char* rowp = Bw + ol * BSTR_B;
                const int sw = (ol & 3) << 4;
                *reinterpret_cast<ushort4*>(rowp + ((iiW * 24 + 0)  ^ sw)) = pa;
                *reinterpret_cast<ushort4*>(rowp + ((iiW * 24 + 8)  ^ sw)) = pb;
                *reinterpret_cast<ushort4*>(rowp + ((iiW * 24 + 16) ^ sw)) = pc;
            }
        }
        __syncthreads();

        // ---- prefetch stage s+2 (lands during MFMA + next convert) ----
        if (s < NS - 2) LOADS(set, s + 2)

        // ---- MFMA: 3 k-steps, 2 m-tiles ----
        {
            const char* Ar = (const char*)&Asm[set][0];
            const char* Br = (const char*)&Bsm[set][0];
            const int orow = nt * 16 + row16;
            const int r0 = (mg * 2) * 16 + row16;
            const int r1 = r0 + 16;
            const int swA = (row16 & 7) << 4;
            const int swB = (orow & 3) << 4;
#pragma unroll
            for (int ks = 0; ks < 3; ++ks) {
                const int pre = ks * 64 + k16 * 16;
                bf16x8 bf = *reinterpret_cast<const bf16x8*>(Br + orow * BSTR_B + (pre ^ swB));
                bf16x8 a0 = *reinterpret_cast<const bf16x8*>(Ar + r0 * ASTR_B + (pre ^ swA));
                bf16x8 a1 = *reinterpret_cast<const bf16x8*>(Ar + r1 * ASTR_B + (pre ^ swA));
                acc0 = __builtin_amdgcn_mfma_f32_16x16x32_bf16(a0, bf, acc0, 0, 0, 0);
                acc1 = __builtin_amdgcn_mfma_f32_16x16x32_bf16(a1, bf, acc1, 0, 0, 0);
            }
        }
        __syncthreads();
    }
#undef LOADS

    // ---- epilogue: f32 partial [chunk][b][o] ----
    float* pbase = partial + (size_t)chunk * (B_DIM * OUT1);
    const int col = o0 + nt * 16 + row16;
    const int rb  = k16 * 4;
#pragma unroll
    for (int r = 0; r < 4; ++r) {
        pbase[(size_t)((mg * 2 + 0) * 16 + rb + r) * OUT1 + col] = acc0[r];
        pbase[(size_t)((mg * 2 + 1) * 16 + rb + r) * OUT1 + col] = acc1[r];
    }
}

// ---------------------------------------------------------------------------
// Kernel R: reduce partials (4-way split over 1024 thr) -> h, selu, layer2.
// ---------------------------------------------------------------------------
#define CPG (NCH / 4)   // 16 chunks per group

__global__ __launch_bounds__(1024) void kan_reduce_l2(const float* __restrict__ partial,
                                                      const float* __restrict__ coef2,
                                                      const float* __restrict__ sb2,
                                                      const float* __restrict__ ssp2,
                                                      float* __restrict__ out) {
    const int b = blockIdx.x;
    const int t = threadIdx.x;
    const int o = t & 255;
    const int g = t >> 8;                    // 0..3
    const float* pp = partial + (size_t)g * CPG * (B_DIM * OUT1)
                              + (size_t)b * OUT1 + o;
    float sum = 0.0f;
#pragma unroll
    for (int c = 0; c < CPG; ++c)
        sum += pp[(size_t)c * (B_DIM * OUT1)];

    __shared__ float hred[4][OUT1];
    hred[g][o] = sum;
    __syncthreads();
    const float hv = hred[0][o] + hred[1][o] + hred[2][o] + hred[3][o];

    const float sh = selu_f(hv);
    float w8[8], sil;
    basis_silu(sh, w8, sil);

    float accs[OUT2];
#pragma unroll
    for (int oo = 0; oo < OUT2; ++oo) {
        const float* cp = coef2 + ((size_t)oo * OUT1 + o) * NB;
        float4 c0 = *reinterpret_cast<const float4*>(cp);
        float4 c1 = *reinterpret_cast<const float4*>(cp + 4);
        float dot = w8[0] * c0.x + w8[1] * c0.y + w8[2] * c0.z + w8[3] * c0.w +
                    w8[4] * c1.x + w8[5] * c1.y + w8[6] * c1.z + w8[7] * c1.w;
        accs[oo] = sb2[oo * OUT1 + o] * sil + ssp2[oo * OUT1 + o] * dot;
    }

    __shared__ float red[16][OUT2];
    const int lane = t & 63, wv = t >> 6;
#pragma unroll
    for (int oo = 0; oo < OUT2; ++oo) {
        float v = accs[oo];
#pragma unroll
        for (int off = 32; off >= 1; off >>= 1) v += __shfl_xor(v, off, 64);
        if (lane == 0) red[wv][oo] = v;
    }
    __syncthreads();
    if (t < OUT2)
        out[b * OUT2 + t] = red[0][t] + red[1][t] + red[2][t] + red[3][t];
}

// ---------------------------------------------------------------------------
extern "C" void kernel_launch(void* const* d_in, const int* in_sizes, int n_in,
                              void* d_out, int out_size, void* d_ws, size_t ws_size,
                              hipStream_t stream) {
    const float* x     = (const float*)d_in[0];
    const float* coef1 = (const float*)d_in[1];
    const float* sb1   = (const float*)d_in[2];
    const float* ssp1  = (const float*)d_in[3];
    const float* coef2 = (const float*)d_in[4];
    const float* sb2   = (const float*)d_in[5];
    const float* ssp2  = (const float*)d_in[6];
    float* out = (float*)d_out;

    float* xT      = (float*)d_ws;                                      // 1.5 MB
    float* partial = (float*)((char*)d_ws + (size_t)IN1 * B_DIM * 4);   // 8.4 MB

    ktranspose<<<dim3(96, 4), dim3(32, 8), 0, stream>>>(x, xT);
    kan_gemm<<<dim3(OUT1 / BN, NCH), 512, 0, stream>>>(xT, coef1, sb1, ssp1, partial);
    kan_reduce_l2<<<B_DIM, 1024, 0, stream>>>(partial, coef2, sb2, ssp2, out);
}

// Round 5
// 44.820 us; speedup vs baseline: 1.0768x; 1.0768x over previous
//
#include <hip/hip_runtime.h>
#include <hip/hip_bf16.h>
#include <math.h>

// ---------------------------------------------------------------------------
// KAN 2-layer forward, decomposed:
//   kconv_a: x(128,3072) -> A bf16 [128][K=27648]  (basis+silu, banded, swizzled)
//   kconv_w: coef1/ssp1/sb1 -> W bf16 [256][K]     (coef*ssp | sb, swizzled)
//   kgemm  : C = A * W^T via MFMA, split-K=108, global_load_lds pipeline
//   kreduce: sum partials -> h, selu, layer2 -> out
// k banding: k = slot*3072 + i, slot 0..7 = basis_g, slot 8 = silu/sb.
// Swizzle: within each 128B chunk (64 k), quad (16B) index ^= (row & 7).
// ---------------------------------------------------------------------------

#define B_DIM   128
#define IN1     3072
#define OUT1    256
#define NB      8
#define OUT2    10

#define KTOT    27648            // 9 * 3072
#define ROWB    55296            // KTOT * 2 bytes per row
#define SPLITK  108              // k-chunks (each 256 k = 4 stages of 64 k)
#define BN      64

typedef short  bf16x8 __attribute__((ext_vector_type(8)));
typedef float  f32x4  __attribute__((ext_vector_type(4)));
typedef unsigned short ushort_t;
typedef unsigned int u32;

__device__ __forceinline__ ushort_t f2bf(float f) {
    union { __hip_bfloat16 h; ushort_t u; } v;
    v.h = __float2bfloat16(f);
    return v.u;
}
__device__ __forceinline__ float bf2f(ushort_t h) {
    union { float f; u32 u; } v; v.u = ((u32)h) << 16;
    return v.f;
}

__device__ __forceinline__ void gl_lds16(const void* g, void* l) {
    __builtin_amdgcn_global_load_lds(
        (const __attribute__((address_space(1))) u32*)g,
        (__attribute__((address_space(3))) u32*)l, 16, 0, 0);
}

// cardinal cubic B-spline basis (8 funcs) + silu, closed form (== Cox-de Boor
// recursion of the reference on the uniform extended grid [-2.2,2.2], h=0.4).
__device__ __forceinline__ void basis_silu(float x, float w[8], float& sil) {
    sil = x / (1.0f + __expf(-x));
    float u  = (x + 2.2f) * 2.5f;
    float uf = floorf(u);
    int   j  = (int)uf;
    float t  = u - uf;
    float omt = 1.0f - t;
    float t2 = t * t, t3 = t2 * t;
    float w0 = omt * omt * omt * (1.0f / 6.0f);
    float w1 = (3.0f * t3 - 6.0f * t2 + 4.0f) * (1.0f / 6.0f);
    float w2 = (-3.0f * t3 + 3.0f * t2 + 3.0f * t + 1.0f) * (1.0f / 6.0f);
    float w3 = t3 * (1.0f / 6.0f);
    bool valid = (u >= 0.0f) && (u < 11.0f);
#pragma unroll
    for (int g = 0; g < 8; ++g) {
        int m = g - j + 3;
        float v = (m == 0) ? w0 : (m == 1) ? w1 : (m == 2) ? w2 : (m == 3) ? w3 : 0.0f;
        w[g] = valid ? v : 0.0f;
    }
}

__device__ __forceinline__ float selu_f(float x) {
    const float scale = 1.0507009873554805f;
    const float alpha = 1.6732632423543772f;
    return (x > 0.0f) ? scale * x : scale * alpha * (__expf(x) - 1.0f);
}

// ---------------------------------------------------------------------------
// kconv_a: thread -> (b, ig of 8 i).  Writes 9 bands x ushort8 (swizzled quad).
// ---------------------------------------------------------------------------
__global__ __launch_bounds__(128) void kconv_a(const float* __restrict__ x,
                                               char* __restrict__ Ag) {
    const int gid = blockIdx.x * 128 + threadIdx.x;        // 0..49151
    const int b  = gid / 384;
    const int ig = gid - b * 384;
    const int i0 = ig * 8;

    float4 x0 = *reinterpret_cast<const float4*>(x + (size_t)b * IN1 + i0);
    float4 x1 = *reinterpret_cast<const float4*>(x + (size_t)b * IN1 + i0 + 4);
    float xa[8] = {x0.x, x0.y, x0.z, x0.w, x1.x, x1.y, x1.z, x1.w};

    float bs[8][8], sil[8];
#pragma unroll
    for (int p = 0; p < 8; ++p) basis_silu(xa[p], bs[p], sil[p]);

    char* rowp = Ag + (size_t)b * ROWB;
    const int qsw = ((ig & 7) ^ (b & 7)) << 4;
#pragma unroll
    for (int s = 0; s < 9; ++s) {
        ushort_t v[8];
#pragma unroll
        for (int p = 0; p < 8; ++p)
            v[p] = f2bf((s < 8) ? bs[p][s] : sil[p]);
        *reinterpret_cast<uint4*>(rowp + (s * 48 + (ig >> 3)) * 128 + qsw) =
            *reinterpret_cast<const uint4*>(v);
    }
}

// ---------------------------------------------------------------------------
// kconv_w: thread -> (o, ig of 8 i).  W[k][o]: slot<8 = coef*ssp, slot8 = sb.
// ---------------------------------------------------------------------------
__global__ __launch_bounds__(128) void kconv_w(const float* __restrict__ coef1,
                                               const float* __restrict__ sb1,
                                               const float* __restrict__ ssp1,
                                               char* __restrict__ Wg) {
    const int gid = blockIdx.x * 128 + threadIdx.x;        // 0..98303
    const int o  = gid / 384;
    const int ig = gid - o * 384;
    const int i0 = ig * 8;

    float cf[8][8], sspv[8], sbv[8];
#pragma unroll
    for (int p = 0; p < 8; ++p) {
        const float* cp = coef1 + ((size_t)o * IN1 + i0 + p) * NB;
        float4 c0 = *reinterpret_cast<const float4*>(cp);
        float4 c1 = *reinterpret_cast<const float4*>(cp + 4);
        cf[p][0] = c0.x; cf[p][1] = c0.y; cf[p][2] = c0.z; cf[p][3] = c0.w;
        cf[p][4] = c1.x; cf[p][5] = c1.y; cf[p][6] = c1.z; cf[p][7] = c1.w;
    }
    {
        float4 s0 = *reinterpret_cast<const float4*>(ssp1 + (size_t)o * IN1 + i0);
        float4 s1 = *reinterpret_cast<const float4*>(ssp1 + (size_t)o * IN1 + i0 + 4);
        sspv[0]=s0.x; sspv[1]=s0.y; sspv[2]=s0.z; sspv[3]=s0.w;
        sspv[4]=s1.x; sspv[5]=s1.y; sspv[6]=s1.z; sspv[7]=s1.w;
        float4 b0 = *reinterpret_cast<const float4*>(sb1 + (size_t)o * IN1 + i0);
        float4 b1 = *reinterpret_cast<const float4*>(sb1 + (size_t)o * IN1 + i0 + 4);
        sbv[0]=b0.x; sbv[1]=b0.y; sbv[2]=b0.z; sbv[3]=b0.w;
        sbv[4]=b1.x; sbv[5]=b1.y; sbv[6]=b1.z; sbv[7]=b1.w;
    }

    char* rowp = Wg + (size_t)o * ROWB;
    const int qsw = ((ig & 7) ^ (o & 7)) << 4;
#pragma unroll
    for (int s = 0; s < 9; ++s) {
        ushort_t v[8];
#pragma unroll
        for (int p = 0; p < 8; ++p)
            v[p] = f2bf((s < 8) ? cf[p][s] * sspv[p] : sbv[p]);
        *reinterpret_cast<uint4*>(rowp + (s * 48 + (ig >> 3)) * 128 + qsw) =
            *reinterpret_cast<const uint4*>(v);
    }
}

// ---------------------------------------------------------------------------
// kgemm: C(128 x 64-per-nt) += A(128,256k) * W(256k,64).  512 thr, grid (4,108).
//   Stage = 64 k (one 128B chunk per row).  2-buffer LDS, counted vmcnt.
// ---------------------------------------------------------------------------
__global__ __launch_bounds__(512) void kgemm(const char* __restrict__ Ag,
                                             const char* __restrict__ Wg,
                                             ushort_t* __restrict__ partial) {
    __shared__ __align__(16) char lds[2][24576];   // per buf: A 16K | W 8K

    const int tid = threadIdx.x;
    const int w   = tid >> 6, l = tid & 63;
    const int nt  = blockIdx.x, kc = blockIdx.y;
    const int o0  = nt * BN;

    // global_load_lds source bases (per-lane), swizzle baked into global layout
    const int ar0 = tid >> 3;                 // A round 0: rows 0..63
    const int ar1 = 64 + (tid >> 3);          // A round 1: rows 64..127
    const int aq  = tid & 7;
    const char* Asrc0 = Ag + (size_t)ar0 * ROWB + ((aq ^ (ar0 & 7)) << 4);
    const char* Asrc1 = Ag + (size_t)ar1 * ROWB + ((aq ^ (ar1 & 7)) << 4);
    const int wr = tid >> 3;                  // W rows 0..63
    const char* Wsrc = Wg + (size_t)(o0 + wr) * ROWB + ((aq ^ (wr & 7)) << 4);

#define ISSUE(ss, buf)                                                        \
    {                                                                         \
        const int cb = (kc * 4 + (ss)) * 128;                                 \
        char* base = &lds[buf][0];                                            \
        gl_lds16(Asrc0 + cb, base + w * 1024);                                \
        gl_lds16(Asrc1 + cb, base + 8192 + w * 1024);                         \
        gl_lds16(Wsrc  + cb, base + 16384 + w * 1024);                        \
    }

    f32x4 acc[2][2];
#pragma unroll
    for (int a = 0; a < 2; ++a)
#pragma unroll
        for (int bq = 0; bq < 2; ++bq) acc[a][bq] = (f32x4){0.f, 0.f, 0.f, 0.f};

    const int mq = w >> 1, nq = w & 1;
    const int r16 = l & 15, k16 = l >> 4;

    ISSUE(0, 0)
    ISSUE(1, 1)

#pragma unroll
    for (int s = 0; s < 4; ++s) {
        if (s < 3) { asm volatile("s_waitcnt vmcnt(3)" ::: "memory"); }
        else       { asm volatile("s_waitcnt vmcnt(0)" ::: "memory"); }
        __builtin_amdgcn_s_barrier();
        asm volatile("" ::: "memory");

        const char* Ab = &lds[s & 1][0];
        const char* Wb = &lds[s & 1][16384];
#pragma unroll
        for (int ks = 0; ks < 2; ++ks) {
            const int qf = ks * 4 + k16;
            bf16x8 bf[2], af[2];
#pragma unroll
            for (int bq = 0; bq < 2; ++bq) {
                const int rn = nq * 32 + bq * 16 + r16;
                bf[bq] = *reinterpret_cast<const bf16x8*>(Wb + rn * 128 + ((qf ^ (rn & 7)) << 4));
            }
#pragma unroll
            for (int a = 0; a < 2; ++a) {
                const int rm = mq * 32 + a * 16 + r16;
                af[a] = *reinterpret_cast<const bf16x8*>(Ab + rm * 128 + ((qf ^ (rm & 7)) << 4));
            }
#pragma unroll
            for (int a = 0; a < 2; ++a)
#pragma unroll
                for (int bq = 0; bq < 2; ++bq)
                    acc[a][bq] = __builtin_amdgcn_mfma_f32_16x16x32_bf16(af[a], bf[bq], acc[a][bq], 0, 0, 0);
        }

        __builtin_amdgcn_s_barrier();
        asm volatile("" ::: "memory");
        if (s == 0) ISSUE(2, 0)
        if (s == 1) ISSUE(3, 1)
    }
#undef ISSUE

    // epilogue: bf16 partial [kc][b][o]
    ushort_t* pp = partial + (size_t)kc * (B_DIM * OUT1);
#pragma unroll
    for (int a = 0; a < 2; ++a) {
#pragma unroll
        for (int bq = 0; bq < 2; ++bq) {
            const int col = o0 + nq * 32 + bq * 16 + r16;
#pragma unroll
            for (int r = 0; r < 4; ++r) {
                const int row = mq * 32 + a * 16 + k16 * 4 + r;
                pp[(size_t)row * OUT1 + col] = f2bf(acc[a][bq][r]);
            }
        }
    }
}

// ---------------------------------------------------------------------------
// kreduce: sum 108 partials (4-way split) -> h, selu, layer2.
// ---------------------------------------------------------------------------
#define CPG (SPLITK / 4)   // 27

__global__ __launch_bounds__(1024) void kreduce(const ushort_t* __restrict__ partial,
                                                const float* __restrict__ coef2,
                                                const float* __restrict__ sb2,
                                                const float* __restrict__ ssp2,
                                                float* __restrict__ out) {
    const int b = blockIdx.x;
    const int t = threadIdx.x;
    const int o = t & 255;
    const int g = t >> 8;                    // 0..3
    const ushort_t* pp = partial + ((size_t)g * CPG * B_DIM + b) * OUT1 + o;
    float sum = 0.0f;
#pragma unroll
    for (int c = 0; c < CPG; ++c)
        sum += bf2f(pp[(size_t)c * (B_DIM * OUT1)]);

    __shared__ float hred[4][OUT1];
    hred[g][o] = sum;
    __syncthreads();
    const float hv = hred[0][o] + hred[1][o] + hred[2][o] + hred[3][o];

    const float sh = selu_f(hv);
    float w8[8], sil;
    basis_silu(sh, w8, sil);

    float accs[OUT2];
#pragma unroll
    for (int oo = 0; oo < OUT2; ++oo) {
        const float* cp = coef2 + ((size_t)oo * OUT1 + o) * NB;
        float4 c0 = *reinterpret_cast<const float4*>(cp);
        float4 c1 = *reinterpret_cast<const float4*>(cp + 4);
        float dot = w8[0] * c0.x + w8[1] * c0.y + w8[2] * c0.z + w8[3] * c0.w +
                    w8[4] * c1.x + w8[5] * c1.y + w8[6] * c1.z + w8[7] * c1.w;
        accs[oo] = sb2[oo * OUT1 + o] * sil + ssp2[oo * OUT1 + o] * dot;
    }

    __shared__ float red[16][OUT2];
    const int lane = t & 63, wv = t >> 6;
#pragma unroll
    for (int oo = 0; oo < OUT2; ++oo) {
        float v = accs[oo];
#pragma unroll
        for (int off = 32; off >= 1; off >>= 1) v += __shfl_xor(v, off, 64);
        if (lane == 0) red[wv][oo] = v;
    }
    __syncthreads();
    if (t < OUT2)
        out[b * OUT2 + t] = red[0][t] + red[1][t] + red[2][t] + red[3][t];
}

// ---------------------------------------------------------------------------
extern "C" void kernel_launch(void* const* d_in, const int* in_sizes, int n_in,
                              void* d_out, int out_size, void* d_ws, size_t ws_size,
                              hipStream_t stream) {
    const float* x     = (const float*)d_in[0];
    const float* coef1 = (const float*)d_in[1];
    const float* sb1   = (const float*)d_in[2];
    const float* ssp1  = (const float*)d_in[3];
    const float* coef2 = (const float*)d_in[4];
    const float* sb2   = (const float*)d_in[5];
    const float* ssp2  = (const float*)d_in[6];
    float* out = (float*)d_out;

    char*     Ag      = (char*)d_ws;                             // 7,077,888 B
    char*     Wg      = Ag + (size_t)B_DIM * ROWB;               // 14,155,776 B
    ushort_t* partial = (ushort_t*)(Wg + (size_t)OUT1 * ROWB);   // 7,077,888 B

    kconv_a<<<384, 128, 0, stream>>>(x, Ag);
    kconv_w<<<768, 128, 0, stream>>>(coef1, sb1, ssp1, Wg);
    kgemm<<<dim3(OUT1 / BN, SPLITK), 512, 0, stream>>>(Ag, Wg, partial);
    kreduce<<<B_DIM, 1024, 0, stream>>>(partial, coef2, sb2, ssp2, out);
}